// Round 1
// baseline (418.623 us; speedup 1.0000x reference)
//
#include <hip/hip_runtime.h>

typedef __bf16 bf16;
typedef __bf16 bf16x4 __attribute__((ext_vector_type(4)));
typedef __bf16 bf16x8 __attribute__((ext_vector_type(8)));
typedef float  f32x4  __attribute__((ext_vector_type(4)));

#define AS1 __attribute__((address_space(1)))
#define AS3 __attribute__((address_space(3)))

__device__ __forceinline__ void gload_lds16(const void* g, void* l) {
    __builtin_amdgcn_global_load_lds((const AS1 void*)g, (AS3 void*)l, 16, 0, 0);
}

// ---------------- elementwise cast f32 -> bf16 (vectorized) ----------------
__global__ __launch_bounds__(256) void cast_f32_to_bf16(
    const float* __restrict__ in, bf16* __restrict__ out, int n4)
{
    int i = blockIdx.x * 256 + threadIdx.x;
    if (i < n4) {
        float4 v = ((const float4*)in)[i];
        bf16x4 o = { (bf16)v.x, (bf16)v.y, (bf16)v.z, (bf16)v.w };
        ((bf16x4*)out)[i] = o;
    }
}

// ---------------- transpose + cast: in[R][C] f32 -> out[C][R] bf16 ----------
__global__ __launch_bounds__(256) void transpose_cast(
    const float* __restrict__ in, bf16* __restrict__ out, int R, int C)
{
    __shared__ float tile[32][33];
    int tx = threadIdx.x & 31, tg = threadIdx.x >> 5;
    int c0 = blockIdx.x * 32, r0 = blockIdx.y * 32;
    #pragma unroll
    for (int j = tg; j < 32; j += 8)
        tile[j][tx] = in[(size_t)(r0 + j) * C + c0 + tx];
    __syncthreads();
    #pragma unroll
    for (int j = tg; j < 32; j += 8)
        out[(size_t)(c0 + j) * R + r0 + tx] = (bf16)tile[tx][j];
}

// ---------------- GEMM: C[M][N] = (A[M][K] @ Bt[N][K]^T + bias) * scale -----
// 128x128 tile, BK=32, 4 waves (2x2 of 64x64), 16x16x32 bf16 MFMA.
// global_load_lds staging with source-side XOR swizzle -> conflict-free ds_read_b128.
template<int OUTBF>
__global__ __launch_bounds__(256) void gemm_bt(
    const bf16* __restrict__ A, const bf16* __restrict__ Bt,
    const float* __restrict__ bias, void* __restrict__ Cv,
    int M, int N, int K, float scale)
{
    __shared__ bf16 As[128 * 32];
    __shared__ bf16 Bs[128 * 32];
    const int tid = threadIdx.x;
    const int l = tid & 63, w = tid >> 6;
    const int wm = w >> 1, wn = w & 1;
    const size_t rowBase = (size_t)blockIdx.y * 128;
    const size_t colBase = (size_t)blockIdx.x * 128;

    f32x4 acc[4][4] = {};

    // staging: wave w covers tile rows [w*32, w*32+32). lane -> (row, swizzled chunk)
    const int srow = l >> 2;                       // row within 16-row issue
    const int schunk = (l & 3) ^ ((l >> 3) & 3);   // source chunk (XOR swizzle)
    // fragment reads
    const int frow = l & 15;
    const int fswz = (frow >> 1) & 3;
    const int g = l >> 4;

    const bf16* Ag = A  + (rowBase + w * 32 + srow) * (size_t)K + schunk * 8;
    const bf16* Bg = Bt + (colBase + w * 32 + srow) * (size_t)K + schunk * 8;

    for (int k0 = 0; k0 < K; k0 += 32) {
        gload_lds16(Ag + k0,            As + (w * 32) * 32);
        gload_lds16(Ag + 16 * (size_t)K + k0, As + (w * 32 + 16) * 32);
        gload_lds16(Bg + k0,            Bs + (w * 32) * 32);
        gload_lds16(Bg + 16 * (size_t)K + k0, Bs + (w * 32 + 16) * 32);
        __syncthreads();

        bf16x8 af[4], bfr[4];
        #pragma unroll
        for (int mi = 0; mi < 4; ++mi)
            af[mi] = *(const bf16x8*)(As + (wm * 64 + mi * 16 + frow) * 32 + ((g ^ fswz) << 3));
        #pragma unroll
        for (int ni = 0; ni < 4; ++ni)
            bfr[ni] = *(const bf16x8*)(Bs + (wn * 64 + ni * 16 + frow) * 32 + ((g ^ fswz) << 3));
        #pragma unroll
        for (int mi = 0; mi < 4; ++mi)
            #pragma unroll
            for (int ni = 0; ni < 4; ++ni)
                acc[mi][ni] = __builtin_amdgcn_mfma_f32_16x16x32_bf16(af[mi], bfr[ni], acc[mi][ni], 0, 0, 0);
        __syncthreads();
    }

    // epilogue: C/D layout col = lane&15, row = (lane>>4)*4 + reg
    const int cr = (l >> 4) * 4;
    const int cc = l & 15;
    #pragma unroll
    for (int ni = 0; ni < 4; ++ni) {
        const int col = (int)colBase + wn * 64 + ni * 16 + cc;
        const float bv = bias[col];
        #pragma unroll
        for (int mi = 0; mi < 4; ++mi) {
            #pragma unroll
            for (int r = 0; r < 4; ++r) {
                const size_t row = rowBase + wm * 64 + mi * 16 + cr + r;
                float v = (acc[mi][ni][r] + bv) * scale;
                if (OUTBF) ((bf16*)Cv)[row * N + col] = (bf16)v;
                else       ((float*)Cv)[row * N + col] = v;
            }
        }
    }
}

// ---------------- fused flash attention -------------------------------------
// grid (S/64, H=16, B=2), 256 threads (4 waves x 16 q-rows). KVBLK=64.
// Q pre-scaled by 1/sqrt(D) in the Q projection.
__global__ __launch_bounds__(256) void attn_fwd(
    const bf16* __restrict__ Q, const bf16* __restrict__ Kb,
    const bf16* __restrict__ Vb, bf16* __restrict__ O)
{
    constexpr int S = 2048;
    __shared__ bf16 Ks[64 * 128];     // [key][d], source-swizzled chunks
    __shared__ bf16 VTs[128 * 64];    // [d][key], swizzled
    __shared__ bf16 Ps[4][16 * 64];   // per-wave P tile [q][key], swizzled

    const int tid = threadIdx.x;
    const int l = tid & 63, w = tid >> 6;
    const int qt = blockIdx.x, h = blockIdx.y, b = blockIdx.z;
    const int kvh = h >> 3;
    const int lg = l >> 4;   // 0..3
    const int ll = l & 15;

    // Q fragments for whole loop: wave's 16 q-rows, full D=128 (4 chunks of 32)
    bf16x8 qf[4];
    {
        const bf16* qp = Q + ((size_t)(b * S + qt * 64 + w * 16 + ll)) * 2048 + h * 128 + lg * 8;
        #pragma unroll
        for (int kd = 0; kd < 4; ++kd) qf[kd] = *(const bf16x8*)(qp + kd * 32);
    }

    f32x4 of[8] = {};
    float mrow[4], lrow[4];
    #pragma unroll
    for (int r = 0; r < 4; ++r) { mrow[r] = -1e30f; lrow[r] = 0.f; }

    const bf16* Kg = Kb + ((size_t)b * S * 2 + kvh) * 128;   // row stride 256 elems
    const bf16* Vg = Vb + ((size_t)b * S * 2 + kvh) * 128;

    for (int kv0 = 0; kv0 < S; kv0 += 64) {
        // ---- stage K tile via global_load_lds (source-side XOR swizzle) ----
        #pragma unroll
        for (int i = 0; i < 4; ++i) {
            int key = w * 16 + i * 4 + lg;
            int sch = (l & 15) ^ (key & 7);
            gload_lds16(Kg + (size_t)(kv0 + key) * 256 + sch * 8, Ks + (w * 16 + i * 4) * 128);
        }
        // ---- stage V^T via register transpose (swizzled scalar writes) ----
        #pragma unroll
        for (int i = 0; i < 4; ++i) {
            int ch = w * 4 + i;   // chunk of 8 d's
            bf16x8 v = *(const bf16x8*)(Vg + (size_t)(kv0 + l) * 256 + ch * 8);
            #pragma unroll
            for (int j = 0; j < 8; ++j) {
                int d = ch * 8 + j;
                VTs[d * 64 + ((((l >> 3) ^ (d & 7))) << 3) + (l & 7)] = v[j];
            }
        }
        __syncthreads();

        // ---- QK^T: scores [16q x 64k] per wave ----
        f32x4 sc[4] = {};
        #pragma unroll
        for (int ni = 0; ni < 4; ++ni) {
            int key = ni * 16 + ll;
            #pragma unroll
            for (int kd = 0; kd < 4; ++kd) {
                int c = kd * 4 + lg;
                bf16x8 kf = *(const bf16x8*)(Ks + key * 128 + ((c ^ (key & 7)) << 3));
                sc[ni] = __builtin_amdgcn_mfma_f32_16x16x32_bf16(qf[kd], kf, sc[ni], 0, 0, 0);
            }
        }

        // ---- online softmax (16-lane groups hold one q-row) ----
        float pv[4][4];
        #pragma unroll
        for (int r = 0; r < 4; ++r) {
            float tm = fmaxf(fmaxf(sc[0][r], sc[1][r]), fmaxf(sc[2][r], sc[3][r]));
            #pragma unroll
            for (int off = 1; off < 16; off <<= 1) tm = fmaxf(tm, __shfl_xor(tm, off, 64));
            float mnew = fmaxf(mrow[r], tm);
            float alpha = __expf(mrow[r] - mnew);
            mrow[r] = mnew;
            float rs = 0.f;
            #pragma unroll
            for (int ni = 0; ni < 4; ++ni) { pv[ni][r] = __expf(sc[ni][r] - mnew); rs += pv[ni][r]; }
            #pragma unroll
            for (int off = 1; off < 16; off <<= 1) rs += __shfl_xor(rs, off, 64);
            lrow[r] = lrow[r] * alpha + rs;
            #pragma unroll
            for (int nf = 0; nf < 8; ++nf) of[nf][r] *= alpha;
        }

        // ---- P -> LDS (bf16, swizzled; per-wave region, same-wave consume) ----
        #pragma unroll
        for (int ni = 0; ni < 4; ++ni) {
            int key = ni * 16 + ll;
            #pragma unroll
            for (int r = 0; r < 4; ++r) {
                int q = lg * 4 + r;
                Ps[w][q * 64 + (((key >> 3) ^ (q & 7)) << 3) + (key & 7)] = (bf16)pv[ni][r];
            }
        }

        // ---- PV: O += P @ V ----
        #pragma unroll
        for (int kk = 0; kk < 2; ++kk) {
            int q = ll;
            int c = kk * 4 + lg;
            bf16x8 pa = *(const bf16x8*)(&Ps[w][q * 64 + ((c ^ (q & 7)) << 3)]);
            #pragma unroll
            for (int nf = 0; nf < 8; ++nf) {
                int d = nf * 16 + ll;
                bf16x8 vb = *(const bf16x8*)(&VTs[d * 64 + ((c ^ (d & 7)) << 3)]);
                of[nf] = __builtin_amdgcn_mfma_f32_16x16x32_bf16(pa, vb, of[nf], 0, 0, 0);
            }
        }
        __syncthreads();
    }

    // ---- normalize + store ----
    #pragma unroll
    for (int r = 0; r < 4; ++r) {
        float inv = 1.0f / lrow[r];
        size_t row = (size_t)b * S + qt * 64 + w * 16 + lg * 4 + r;
        bf16* op = O + row * 2048 + h * 128 + ll;
        #pragma unroll
        for (int nf = 0; nf < 8; ++nf)
            op[nf * 16] = (bf16)(of[nf][r] * inv);
    }
}

// ---------------- launcher ---------------------------------------------------
extern "C" void kernel_launch(void* const* d_in, const int* in_sizes, int n_in,
                              void* d_out, int out_size, void* d_ws, size_t ws_size,
                              hipStream_t stream)
{
    const float* X  = (const float*)d_in[0];
    const float* Wq = (const float*)d_in[1];
    const float* bq = (const float*)d_in[2];
    const float* Wk = (const float*)d_in[3];
    const float* bk = (const float*)d_in[4];
    const float* Wv = (const float*)d_in[5];
    const float* bv = (const float*)d_in[6];
    const float* Wo = (const float*)d_in[7];
    const float* bo = (const float*)d_in[8];
    float* out = (float*)d_out;

    // workspace layout (bf16 elements)
    bf16* p = (bf16*)d_ws;
    bf16* Xb   = p; p += 8388608;   // [4096][2048] X bf16 (reused as attn output)
    bf16* Qb   = p; p += 8388608;   // [4096][2048]
    bf16* Kbuf = p; p += 1048576;   // [4096][256]
    bf16* Vbuf = p; p += 1048576;   // [4096][256]
    bf16* Wqt  = p; p += 4194304;   // [2048][2048]
    bf16* Wkt  = p; p += 524288;    // [256][2048]
    bf16* Wvt  = p; p += 524288;    // [256][2048]
    bf16* Wot  = p; p += 4194304;   // [2048][2048]
    bf16* Oattn = Xb;               // alias: X dead after V projection

    const float qscale = 0.08838834764831845f;  // 1/sqrt(128)

    cast_f32_to_bf16<<<8192, 256, 0, stream>>>(X, Xb, 2097152);
    transpose_cast<<<dim3(64, 64), 256, 0, stream>>>(Wq, Wqt, 2048, 2048);
    transpose_cast<<<dim3(8, 64),  256, 0, stream>>>(Wk, Wkt, 2048, 256);
    transpose_cast<<<dim3(8, 64),  256, 0, stream>>>(Wv, Wvt, 2048, 256);
    transpose_cast<<<dim3(64, 64), 256, 0, stream>>>(Wo, Wot, 2048, 2048);

    gemm_bt<1><<<dim3(16, 32), 256, 0, stream>>>(Xb, Wqt, bq, Qb,   4096, 2048, 2048, qscale);
    gemm_bt<1><<<dim3(2, 32),  256, 0, stream>>>(Xb, Wkt, bk, Kbuf, 4096, 256,  2048, 1.0f);
    gemm_bt<1><<<dim3(2, 32),  256, 0, stream>>>(Xb, Wvt, bv, Vbuf, 4096, 256,  2048, 1.0f);

    attn_fwd<<<dim3(32, 16, 2), 256, 0, stream>>>(Qb, Kbuf, Vbuf, Oattn);

    gemm_bt<0><<<dim3(16, 32), 256, 0, stream>>>(Oattn, Wot, bo, out, 4096, 2048, 2048, 1.0f);
}

// Round 2
// 306.232 us; speedup vs baseline: 1.3670x; 1.3670x over previous
//
#include <hip/hip_runtime.h>

typedef __bf16 bf16;
typedef __bf16 bf16x4 __attribute__((ext_vector_type(4)));
typedef __bf16 bf16x8 __attribute__((ext_vector_type(8)));
typedef float  f32x4  __attribute__((ext_vector_type(4)));

#define AS1 __attribute__((address_space(1)))
#define AS3 __attribute__((address_space(3)))

__device__ __forceinline__ void gload_lds16(const void* g, void* l) {
    __builtin_amdgcn_global_load_lds((const AS1 void*)g, (AS3 void*)l, 16, 0, 0);
}

// ---------------- elementwise cast f32 -> bf16 (vectorized) ----------------
__global__ __launch_bounds__(256) void cast_f32_to_bf16(
    const float* __restrict__ in, bf16* __restrict__ out, int n4)
{
    int i = blockIdx.x * 256 + threadIdx.x;
    if (i < n4) {
        float4 v = ((const float4*)in)[i];
        bf16x4 o = { (bf16)v.x, (bf16)v.y, (bf16)v.z, (bf16)v.w };
        ((bf16x4*)out)[i] = o;
    }
}

// ---------------- transpose + cast: in[R][C] f32 -> out[C][R] bf16 ----------
__global__ __launch_bounds__(256) void transpose_cast(
    const float* __restrict__ in, bf16* __restrict__ out, int R, int C)
{
    __shared__ float tile[32][33];
    int tx = threadIdx.x & 31, tg = threadIdx.x >> 5;
    int c0 = blockIdx.x * 32, r0 = blockIdx.y * 32;
    #pragma unroll
    for (int j = tg; j < 32; j += 8)
        tile[j][tx] = in[(size_t)(r0 + j) * C + c0 + tx];
    __syncthreads();
    #pragma unroll
    for (int j = tg; j < 32; j += 8)
        out[(size_t)(c0 + j) * R + r0 + tx] = (bf16)tile[tx][j];
}

// ---------------- concat bias: [bk(256) || bv(256)] -------------------------
__global__ void concat_bias_kv(const float* __restrict__ bk,
                               const float* __restrict__ bv, float* __restrict__ o)
{
    int i = blockIdx.x * 256 + threadIdx.x;
    if (i < 256) o[i] = bk[i];
    else if (i < 512) o[i] = bv[i - 256];
}

// ---------------- GEMM: C[M][N] = (A[M][K] @ Bt[N][K]^T + bias) * scale -----
template<int OUTBF>
__global__ __launch_bounds__(256) void gemm_bt(
    const bf16* __restrict__ A, const bf16* __restrict__ Bt,
    const float* __restrict__ bias, void* __restrict__ Cv,
    int M, int N, int K, float scale)
{
    __shared__ bf16 As[128 * 32];
    __shared__ bf16 Bs[128 * 32];
    const int tid = threadIdx.x;
    const int l = tid & 63, w = tid >> 6;
    const int wm = w >> 1, wn = w & 1;
    const size_t rowBase = (size_t)blockIdx.y * 128;
    const size_t colBase = (size_t)blockIdx.x * 128;

    f32x4 acc[4][4] = {};

    const int srow = l >> 2;
    const int schunk = (l & 3) ^ ((l >> 3) & 3);
    const int frow = l & 15;
    const int fswz = (frow >> 1) & 3;
    const int g = l >> 4;

    const bf16* Ag = A  + (rowBase + w * 32 + srow) * (size_t)K + schunk * 8;
    const bf16* Bg = Bt + (colBase + w * 32 + srow) * (size_t)K + schunk * 8;

    for (int k0 = 0; k0 < K; k0 += 32) {
        gload_lds16(Ag + k0,                  As + (w * 32) * 32);
        gload_lds16(Ag + 16 * (size_t)K + k0, As + (w * 32 + 16) * 32);
        gload_lds16(Bg + k0,                  Bs + (w * 32) * 32);
        gload_lds16(Bg + 16 * (size_t)K + k0, Bs + (w * 32 + 16) * 32);
        __syncthreads();

        bf16x8 af[4], bfr[4];
        #pragma unroll
        for (int mi = 0; mi < 4; ++mi)
            af[mi] = *(const bf16x8*)(As + (wm * 64 + mi * 16 + frow) * 32 + ((g ^ fswz) << 3));
        #pragma unroll
        for (int ni = 0; ni < 4; ++ni)
            bfr[ni] = *(const bf16x8*)(Bs + (wn * 64 + ni * 16 + frow) * 32 + ((g ^ fswz) << 3));
        #pragma unroll
        for (int mi = 0; mi < 4; ++mi)
            #pragma unroll
            for (int ni = 0; ni < 4; ++ni)
                acc[mi][ni] = __builtin_amdgcn_mfma_f32_16x16x32_bf16(af[mi], bfr[ni], acc[mi][ni], 0, 0, 0);
        __syncthreads();
    }

    const int cr = (l >> 4) * 4;
    const int cc = l & 15;
    #pragma unroll
    for (int ni = 0; ni < 4; ++ni) {
        const int col = (int)colBase + wn * 64 + ni * 16 + cc;
        const float bv = bias[col];
        #pragma unroll
        for (int mi = 0; mi < 4; ++mi) {
            #pragma unroll
            for (int r = 0; r < 4; ++r) {
                const size_t row = rowBase + wm * 64 + mi * 16 + cr + r;
                float v = (acc[mi][ni][r] + bv) * scale;
                if (OUTBF) ((bf16*)Cv)[row * N + col] = (bf16)v;
                else       ((float*)Cv)[row * N + col] = v;
            }
        }
    }
}

// ---------------- fused flash attention (swapped-QK^T, in-register P) -------
// grid (S/64, H=16, B=2), 256 threads (4 waves x 16 q-rows). KVBLK=64.
// Q pre-scaled by 1/sqrt(D). KV buffer is fused [4096][512]: K at kvh*128, V at 256+kvh*128.
__global__ __launch_bounds__(256) void attn_fwd(
    const bf16* __restrict__ Q, const bf16* __restrict__ KV, bf16* __restrict__ O)
{
    constexpr int S = 2048;
    constexpr int LDKV = 512;
    __shared__ bf16 Ks[64 * 128];     // [key][d], source-swizzled chunks
    __shared__ bf16 VTs[128 * 64];    // [d][vslot], pi-permuted keys, swizzled

    const int tid = threadIdx.x;
    const int l = tid & 63, w = tid >> 6;
    const int qt = blockIdx.x, h = blockIdx.y, b = blockIdx.z;
    const int kvh = h >> 3;
    const int lg = l >> 4, ll = l & 15;

    // Q fragments (B-operand layout: lane holds q=ll, d = kd*32 + lg*8 + {0..7})
    bf16x8 qf[4];
    {
        const bf16* qp = Q + ((size_t)(b * S + qt * 64 + w * 16 + ll)) * 2048 + h * 128 + lg * 8;
        #pragma unroll
        for (int kd = 0; kd < 4; ++kd) qf[kd] = *(const bf16x8*)(qp + kd * 32);
    }

    const bf16* Kg = KV + (size_t)b * S * LDKV + kvh * 128;
    const bf16* Vg = Kg + 256;

    f32x4 of[8] = {};
    float m_run = -1e30f, l_run = 0.f;

    // pi^-1: actual key (this lane's staged V row) -> virtual slot, so that
    // the PV A-frag is the lane's own P values in natural pack order.
    const int vslot = ((l >> 5) << 5) + (((l >> 2) & 3) << 3) + (((l >> 4) & 1) << 2) + (l & 3);

    // ---- prologue: stage tile 0 ----
    #pragma unroll
    for (int i = 0; i < 4; ++i) {
        int key = w * 16 + i * 4 + lg;
        int sch = ll ^ (key & 7);
        gload_lds16(Kg + (size_t)key * LDKV + sch * 8, Ks + (w * 16 + i * 4) * 128);
    }
    #pragma unroll
    for (int i = 0; i < 4; ++i) {
        int ch = w * 4 + i;
        bf16x8 v = *(const bf16x8*)(Vg + (size_t)l * LDKV + ch * 8);
        #pragma unroll
        for (int j = 0; j < 8; ++j) {
            int d = ch * 8 + j;
            VTs[d * 64 + (((vslot >> 3) ^ (d & 7)) << 3) + (vslot & 7)] = v[j];
        }
    }
    __syncthreads();

    for (int kv0 = 0; kv0 < S; kv0 += 64) {
        const bool hasNext = (kv0 + 64) < S;
        // issue next tile's V loads early (latency hides under compute)
        bf16x8 vn[4];
        if (hasNext) {
            #pragma unroll
            for (int i = 0; i < 4; ++i)
                vn[i] = *(const bf16x8*)(Vg + (size_t)(kv0 + 64 + l) * LDKV + (w * 4 + i) * 8);
        }

        // ---- QK^T swapped: sc[ni] = P^T frag; lane holds q=ll, key=16ni+lg*4+r
        f32x4 sc[4] = {};
        __builtin_amdgcn_s_setprio(1);
        #pragma unroll
        for (int ni = 0; ni < 4; ++ni) {
            int key = ni * 16 + ll;
            #pragma unroll
            for (int kd = 0; kd < 4; ++kd) {
                bf16x8 kf = *(const bf16x8*)(Ks + key * 128 + (((kd * 4 + lg) ^ (key & 7)) << 3));
                sc[ni] = __builtin_amdgcn_mfma_f32_16x16x32_bf16(kf, qf[kd], sc[ni], 0, 0, 0);
            }
        }
        __builtin_amdgcn_s_setprio(0);

        // ---- online softmax, fully in-lane for q=ll ----
        float tm = sc[0][0];
        #pragma unroll
        for (int ni = 0; ni < 4; ++ni)
            #pragma unroll
            for (int r = 0; r < 4; ++r) tm = fmaxf(tm, sc[ni][r]);
        tm = fmaxf(tm, __shfl_xor(tm, 16, 64));
        tm = fmaxf(tm, __shfl_xor(tm, 32, 64));

        if (!__all(tm <= m_run + 8.f)) {   // defer-max (T13)
            float mnew = fmaxf(m_run, tm);
            float alpha = __expf(m_run - mnew);
            m_run = mnew;
            l_run *= alpha;
            #pragma unroll
            for (int r = 0; r < 4; ++r) {
                float ar = __shfl(alpha, (l & 48) | (lg * 4 + r), 64);
                #pragma unroll
                for (int nf = 0; nf < 8; ++nf) of[nf][r] *= ar;
            }
        }

        float p[4][4];
        float rs = 0.f;
        #pragma unroll
        for (int ni = 0; ni < 4; ++ni)
            #pragma unroll
            for (int r = 0; r < 4; ++r) { p[ni][r] = __expf(sc[ni][r] - m_run); rs += p[ni][r]; }
        rs += __shfl_xor(rs, 16, 64);
        rs += __shfl_xor(rs, 32, 64);
        l_run += rs;

        // ---- pack P -> PV A-frags, fully in-lane ----
        bf16x8 pa[2];
        #pragma unroll
        for (int c = 0; c < 2; ++c)
            #pragma unroll
            for (int e = 0; e < 8; ++e)
                pa[c][e] = (bf16)p[2 * c + (e >> 2)][e & 3];

        // ---- PV: O += P @ V (V in pi-permuted key order) ----
        __builtin_amdgcn_s_setprio(1);
        #pragma unroll
        for (int c = 0; c < 2; ++c) {
            #pragma unroll
            for (int nf = 0; nf < 8; ++nf) {
                int d = nf * 16 + ll;
                bf16x8 vb = *(const bf16x8*)(VTs + d * 64 + (((c * 4 + lg) ^ (d & 7)) << 3));
                of[nf] = __builtin_amdgcn_mfma_f32_16x16x32_bf16(pa[c], vb, of[nf], 0, 0, 0);
            }
        }
        __builtin_amdgcn_s_setprio(0);

        __syncthreads();   // all waves done reading Ks/VTs
        if (hasNext) {
            #pragma unroll
            for (int i = 0; i < 4; ++i) {
                int key = w * 16 + i * 4 + lg;
                int sch = ll ^ (key & 7);
                gload_lds16(Kg + (size_t)(kv0 + 64 + key) * LDKV + sch * 8, Ks + (w * 16 + i * 4) * 128);
            }
            #pragma unroll
            for (int i = 0; i < 4; ++i) {
                int ch = w * 4 + i;
                #pragma unroll
                for (int j = 0; j < 8; ++j) {
                    int d = ch * 8 + j;
                    VTs[d * 64 + (((vslot >> 3) ^ (d & 7)) << 3) + (vslot & 7)] = vn[i][j];
                }
            }
        }
        __syncthreads();   // next tile staged
    }

    // ---- normalize + store ----
    #pragma unroll
    for (int r = 0; r < 4; ++r) {
        float ls = __shfl(l_run, (l & 48) | (lg * 4 + r), 64);
        float inv = 1.0f / ls;
        size_t row = (size_t)(b * S + qt * 64 + w * 16 + lg * 4 + r);
        bf16* op = O + row * 2048 + h * 128 + ll;
        #pragma unroll
        for (int nf = 0; nf < 8; ++nf)
            op[nf * 16] = (bf16)(of[nf][r] * inv);
    }
}

// ---------------- launcher ---------------------------------------------------
extern "C" void kernel_launch(void* const* d_in, const int* in_sizes, int n_in,
                              void* d_out, int out_size, void* d_ws, size_t ws_size,
                              hipStream_t stream)
{
    const float* X  = (const float*)d_in[0];
    const float* Wq = (const float*)d_in[1];
    const float* bq = (const float*)d_in[2];
    const float* Wk = (const float*)d_in[3];
    const float* bk = (const float*)d_in[4];
    const float* Wv = (const float*)d_in[5];
    const float* bv = (const float*)d_in[6];
    const float* Wo = (const float*)d_in[7];
    const float* bo = (const float*)d_in[8];
    float* out = (float*)d_out;

    // workspace layout (bf16 elements)
    bf16* p = (bf16*)d_ws;
    bf16* Xb    = p; p += 8388608;   // [4096][2048] X bf16 (reused as attn output)
    bf16* Qb    = p; p += 8388608;   // [4096][2048]
    bf16* KVbuf = p; p += 2097152;   // [4096][512] : K cols 0-255, V cols 256-511
    bf16* Wqt   = p; p += 4194304;   // [2048][2048]
    bf16* Wkvt  = p; p += 1048576;   // [512][2048] : Wk^T rows 0-255, Wv^T rows 256-511
    bf16* Wot   = p; p += 4194304;   // [2048][2048]
    float* bkv  = (float*)p; p += 1024;  // 512 floats
    bf16* Oattn = Xb;                // alias: X dead after KV projection

    const float qscale = 0.08838834764831845f;  // 1/sqrt(128)

    cast_f32_to_bf16<<<8192, 256, 0, stream>>>(X, Xb, 2097152);
    transpose_cast<<<dim3(64, 64), 256, 0, stream>>>(Wq, Wqt, 2048, 2048);
    transpose_cast<<<dim3(8, 64),  256, 0, stream>>>(Wk, Wkvt, 2048, 256);
    transpose_cast<<<dim3(8, 64),  256, 0, stream>>>(Wv, Wkvt + 256 * 2048, 2048, 256);
    transpose_cast<<<dim3(64, 64), 256, 0, stream>>>(Wo, Wot, 2048, 2048);
    concat_bias_kv<<<2, 256, 0, stream>>>(bk, bv, bkv);

    gemm_bt<1><<<dim3(16, 32), 256, 0, stream>>>(Xb, Wqt, bq, Qb, 4096, 2048, 2048, qscale);
    gemm_bt<1><<<dim3(4, 32),  256, 0, stream>>>(Xb, Wkvt, bkv, KVbuf, 4096, 512, 2048, 1.0f);

    attn_fwd<<<dim3(32, 16, 2), 256, 0, stream>>>(Qb, KVbuf, Oattn);

    gemm_bt<0><<<dim3(16, 32), 256, 0, stream>>>(Oattn, Wot, bo, out, 4096, 2048, 2048, 1.0f);
}